// Round 1
// baseline (624.458 us; speedup 1.0000x reference)
//
#include <hip/hip_runtime.h>
#include <hip/hip_bf16.h>

typedef unsigned short u16;
typedef __attribute__((ext_vector_type(8))) short bf16x8;
typedef __attribute__((ext_vector_type(4))) float f32x4;

__device__ __forceinline__ u16 f2b(float f) {
  union { __hip_bfloat16 h; u16 u; } cv;
  cv.h = __float2bfloat16(f);
  return cv.u;
}
__device__ __forceinline__ float b2f(u16 u) {
  union { unsigned int i; float f; } cv;
  cv.i = ((unsigned int)u) << 16;
  return cv.f;
}

// ---------- f32 -> bf16 conversion, 4 elems/thread, exact grid ----------
__global__ void cvt_bf16(const float* __restrict__ in, u16* __restrict__ out) {
  size_t i = ((size_t)blockIdx.x * 256 + threadIdx.x) * 4;
  float4 v = *(const float4*)(in + i);
  ushort4 o;
  o.x = f2b(v.x); o.y = f2b(v.y); o.z = f2b(v.z); o.w = f2b(v.w);
  *(ushort4*)(out + i) = o;
}

// ---------- RoPE cos/sin table: [L=2048][half=32] ----------
__global__ void rope_tab_k(float2* __restrict__ tab) {
  int t = blockIdx.x * 256 + threadIdx.x;   // 65536
  int l = t >> 5, i = t & 31;
  float inv = powf(10000.0f, -(float)i * (1.0f / 32.0f));
  float ang = (float)l * inv;
  tab[t] = make_float2(cosf(ang), sinf(ang));
}

// ---------- apply RoPE in-place to q,k thirds of qkv (bf16) ----------
__global__ void rope_apply_k(u16* __restrict__ qkv, const float2* __restrict__ tab) {
  int idx = blockIdx.x * 256 + threadIdx.x;   // 8192*32*32 = 8388608
  int i = idx & 31, h = (idx >> 5) & 31, row = idx >> 10;
  int l = row & 2047;
  float2 cs = tab[(l << 5) + i];
  size_t base = (size_t)row * 6144 + h * 64;
  #pragma unroll
  for (int t = 0; t < 2; ++t) {   // q then k
    float x1 = b2f(qkv[base + i]);
    float x2 = b2f(qkv[base + 32 + i]);
    qkv[base + i]      = f2b(x1 * cs.x - x2 * cs.y);
    qkv[base + 32 + i] = f2b(x1 * cs.y + x2 * cs.x);
    base += 2048;
  }
}

// ---------- GEMM C[m,n] = sum_k A[m,k]*B[n,k] (+bias), m97 structure ----------
// A: [M][2048] bf16 row-major, B: [N][2048] bf16 row-major (B^T layout)
template<bool BF16OUT>
__global__ __launch_bounds__(256) void gemm_bt(const u16* __restrict__ A,
                                               const u16* __restrict__ Bm,
                                               const float* __restrict__ bias,
                                               u16* __restrict__ Cb,
                                               float* __restrict__ Cf,
                                               int Ncols) {
  __shared__ u16 As[128 * 32];
  __shared__ u16 Bs[128 * 32];
  const int tid = threadIdx.x;
  const int lane = tid & 63, wid = tid >> 6;
  const int wr = wid >> 1, wc = wid & 1;
  const int m0 = blockIdx.y * 128, n0 = blockIdx.x * 128;
  const int lrow = lane >> 2;          // row within a 16-row chunk
  const int lcb  = (lane & 3) * 16;    // byte offset within 64B row
  const int fr = lane & 15;
  const int fkb = (lane >> 4) * 16;    // frag k byte offset
  f32x4 acc[4][4] = {};
  for (int k0 = 0; k0 < 2048; k0 += 32) {
    #pragma unroll
    for (int j = 0; j < 2; ++j) {
      int chunk = wid * 2 + j;               // 0..7, 16 rows each
      int row = chunk * 16 + lrow;
      const char* ga = (const char*)(A + (size_t)(m0 + row) * 2048 + k0) + lcb;
      const char* gb = (const char*)(Bm + (size_t)(n0 + row) * 2048 + k0) + lcb;
      __builtin_amdgcn_global_load_lds((const __attribute__((address_space(1))) unsigned int*)ga,
                                       (__attribute__((address_space(3))) unsigned int*)(As + chunk * 512),
                                       16, 0, 0);
      __builtin_amdgcn_global_load_lds((const __attribute__((address_space(1))) unsigned int*)gb,
                                       (__attribute__((address_space(3))) unsigned int*)(Bs + chunk * 512),
                                       16, 0, 0);
    }
    __syncthreads();
    bf16x8 af[4], bfr[4];
    #pragma unroll
    for (int m = 0; m < 4; ++m)
      af[m] = *(const bf16x8*)((const char*)As + (wr * 64 + m * 16 + fr) * 64 + fkb);
    #pragma unroll
    for (int n = 0; n < 4; ++n)
      bfr[n] = *(const bf16x8*)((const char*)Bs + (wc * 64 + n * 16 + fr) * 64 + fkb);
    #pragma unroll
    for (int m = 0; m < 4; ++m)
      #pragma unroll
      for (int n = 0; n < 4; ++n)
        acc[m][n] = __builtin_amdgcn_mfma_f32_16x16x32_bf16(af[m], bfr[n], acc[m][n], 0, 0, 0);
    __syncthreads();
  }
  #pragma unroll
  for (int m = 0; m < 4; ++m) {
    #pragma unroll
    for (int n = 0; n < 4; ++n) {
      int gcol = n0 + wc * 64 + n * 16 + fr;
      int grow0 = m0 + wr * 64 + m * 16 + (lane >> 4) * 4;
      float bv = bias[gcol];
      #pragma unroll
      for (int r = 0; r < 4; ++r) {
        float v = acc[m][n][r] + bv;
        if (BF16OUT) Cb[(size_t)(grow0 + r) * Ncols + gcol] = f2b(v);
        else         Cf[(size_t)(grow0 + r) * Ncols + gcol] = v;
      }
    }
  }
}

// ---------- banded attention with sinks ----------
// block = (b, h, n); 4 waves x 16 q-rows. Keys: [0,16)=sinks, [16,208)=band, [208,224)=pad
#define PSTR 232
__global__ __launch_bounds__(256) void attn_k(const u16* __restrict__ qkv,
                                              const float* __restrict__ sinks,
                                              u16* __restrict__ O) {
  __shared__ char smem[59392];
  char* Kraw = smem;                      // phase 1: K_all [224][64] bf16, XOR-swizzled
  char* Qraw = smem + 28672;              // phase 1: Q [64][64] bf16, XOR-swizzled
  u16* Ps = (u16*)smem;                   // phase 2: P [64][PSTR]
  u16* Vt = (u16*)(smem + 29696);         // phase 2: V^T [64][PSTR]
  const int tid = threadIdx.x, lane = tid & 63, wid = tid >> 6;
  const int fr = lane & 15, fk = lane >> 4;
  const int bx = blockIdx.x;
  const int n = bx & 31, h = (bx >> 5) & 31, b = bx >> 10;
  const size_t qrow0 = (size_t)b * 2048 + n * 64;

  // ---- phase 1: stage Q and K_all
  for (int c = tid; c < 512; c += 256) {          // Q: 64 rows x 128B
    int row = c >> 3, colb = (c & 7) * 16;
    uint4 v = *(const uint4*)((const char*)(qkv + (qrow0 + row) * 6144 + h * 64) + colb);
    *(uint4*)(Qraw + ((row * 128 + colb) ^ ((row & 7) << 4))) = v;
  }
  {                                               // sinks -> K rows 0..15 (fp32->bf16)
    int row = tid >> 4, col4 = (tid & 15) * 4;
    float4 v = *(const float4*)(sinks + ((size_t)h * 16 + row) * 64 + col4);
    ushort4 o; o.x = f2b(v.x); o.y = f2b(v.y); o.z = f2b(v.z); o.w = f2b(v.w);
    *(ushort4*)(Kraw + ((row * 128 + col4 * 2) ^ ((row & 7) << 4))) = o;
  }
  for (int c = tid; c < 1536; c += 256) {         // band K -> rows 16..207
    int kidx = c >> 3, colb = (c & 7) * 16;
    int blk = n - 1 + (kidx >> 6);
    int blkc = min(max(blk, 0), 31);
    int kpos = blkc * 64 + (kidx & 63);
    uint4 v = *(const uint4*)((const char*)(qkv + ((size_t)b * 2048 + kpos) * 6144 + 2048 + h * 64) + colb);
    int row = 16 + kidx;
    *(uint4*)(Kraw + ((row * 128 + colb) ^ ((row & 7) << 4))) = v;
  }
  if (tid < 128) {                                // zero pad rows 208..223
    int row = 208 + (tid >> 3), colb = (tid & 7) * 16;
    uint4 z = {0, 0, 0, 0};
    *(uint4*)(Kraw + ((row * 128 + colb) ^ ((row & 7) << 4))) = z;
  }
  __syncthreads();

  // ---- phase 2: QK^T (MFMA) + masked online softmax in registers
  bf16x8 qf[2];
  {
    int qrow = wid * 16 + fr;
    #pragma unroll
    for (int kc = 0; kc < 2; ++kc)
      qf[kc] = *(const bf16x8*)(Qraw + ((qrow * 128 + kc * 64 + fk * 16) ^ ((qrow & 7) << 4)));
  }
  f32x4 sacc[14];
  #pragma unroll
  for (int g = 0; g < 14; ++g) {
    int key = g * 16 + fr;
    bf16x8 kf0 = *(const bf16x8*)(Kraw + ((key * 128 + fk * 16) ^ ((key & 7) << 4)));
    bf16x8 kf1 = *(const bf16x8*)(Kraw + ((key * 128 + 64 + fk * 16) ^ ((key & 7) << 4)));
    f32x4 a = {};
    a = __builtin_amdgcn_mfma_f32_16x16x32_bf16(qf[0], kf0, a, 0, 0, 0);
    a = __builtin_amdgcn_mfma_f32_16x16x32_bf16(qf[1], kf1, a, 0, 0, 0);
    sacc[g] = a;
  }
  float rowmax[4] = {-3e38f, -3e38f, -3e38f, -3e38f};
  #pragma unroll
  for (int g = 0; g < 14; ++g) {
    int key = g * 16 + fr;
    #pragma unroll
    for (int r = 0; r < 4; ++r) {
      float s = sacc[g][r] * 0.125f;
      bool valid;
      if (key < 16) valid = true;
      else if (key < 208) {
        int kidx = key - 16;
        int blk = n - 1 + (kidx >> 6);
        int kpos = blk * 64 + (kidx & 63);
        int qpos = n * 64 + wid * 16 + fk * 4 + r;
        valid = (blk >= 0) && (blk < 32) && (qpos - kpos <= 64) && (kpos - qpos <= 64);
      } else valid = false;
      s = valid ? s : -1e30f;
      sacc[g][r] = s;
      rowmax[r] = fmaxf(rowmax[r], s);
    }
  }
  #pragma unroll
  for (int d = 1; d < 16; d <<= 1)
    #pragma unroll
    for (int r = 0; r < 4; ++r)
      rowmax[r] = fmaxf(rowmax[r], __shfl_xor(rowmax[r], d));
  float rowsum[4] = {0, 0, 0, 0};
  #pragma unroll
  for (int g = 0; g < 14; ++g)
    #pragma unroll
    for (int r = 0; r < 4; ++r) {
      float p = __expf(sacc[g][r] - rowmax[r]);
      sacc[g][r] = p;
      rowsum[r] += p;
    }
  #pragma unroll
  for (int d = 1; d < 16; d <<= 1)
    #pragma unroll
    for (int r = 0; r < 4; ++r)
      rowsum[r] += __shfl_xor(rowsum[r], d);
  __syncthreads();   // Kall/Q now dead; P/Vt regions become writable

  // ---- phase 3: write unnormalized P (bf16), stage V transposed
  #pragma unroll
  for (int g = 0; g < 14; ++g)
    #pragma unroll
    for (int r = 0; r < 4; ++r)
      Ps[(wid * 16 + fk * 4 + r) * PSTR + g * 16 + fr] = f2b(sacc[g][r]);
  {
    int dout = tid & 63, kb = tid >> 6;
    #pragma unroll
    for (int key = kb; key < 16; key += 4)        // sink V rows
      Vt[dout * PSTR + key] = f2b(sinks[((size_t)h * 16 + key) * 64 + dout]);
    for (int kidx = kb; kidx < 192; kidx += 4) {  // band V rows
      int blk = n - 1 + (kidx >> 6);
      int blkc = min(max(blk, 0), 31);
      int kpos = blkc * 64 + (kidx & 63);
      Vt[dout * PSTR + 16 + kidx] = qkv[((size_t)b * 2048 + kpos) * 6144 + 4096 + h * 64 + dout];
    }
    #pragma unroll
    for (int key = 208 + kb; key < 224; key += 4) // zero the pad keys (avoid 0*NaN)
      Vt[dout * PSTR + key] = 0;
  }
  __syncthreads();

  // ---- phase 4: O = P * V  (A=P[q][key], B[col=dout][k=key] = Vt[dout][key])
  f32x4 oacc[4] = {};
  #pragma unroll
  for (int kc = 0; kc < 7; ++kc) {
    bf16x8 pf = *(const bf16x8*)(Ps + (wid * 16 + fr) * PSTR + kc * 32 + fk * 8);
    #pragma unroll
    for (int gd = 0; gd < 4; ++gd) {
      bf16x8 vf = *(const bf16x8*)(Vt + (gd * 16 + fr) * PSTR + kc * 32 + fk * 8);
      oacc[gd] = __builtin_amdgcn_mfma_f32_16x16x32_bf16(pf, vf, oacc[gd], 0, 0, 0);
    }
  }
  #pragma unroll
  for (int gd = 0; gd < 4; ++gd)
    #pragma unroll
    for (int r = 0; r < 4; ++r) {
      int qrl = wid * 16 + fk * 4 + r;
      float v = oacc[gd][r] / rowsum[r];
      O[(qrow0 + qrl) * 2048 + h * 64 + gd * 16 + fr] = f2b(v);
    }
}

extern "C" void kernel_launch(void* const* d_in, const int* in_sizes, int n_in,
                              void* d_out, int out_size, void* d_ws, size_t ws_size,
                              hipStream_t stream) {
  const float* u     = (const float*)d_in[0];
  const float* Wqkv  = (const float*)d_in[1];
  const float* bqkv  = (const float*)d_in[2];
  const float* Wo    = (const float*)d_in[3];
  const float* bo    = (const float*)d_in[4];
  const float* sinks = (const float*)d_in[5];
  float* out = (float*)d_out;

  char* ws = (char*)d_ws;
  u16* u_bf   = (u16*)ws;                      // 33,554,432 B  (reused as O_bf)
  u16* w1_bf  = (u16*)(ws + 33554432);         // 25,165,824 B  (reused for Wo)
  u16* qkv_bf = (u16*)(ws + 58720256);         // 100,663,296 B
  float2* tab = (float2*)(ws + 159383552);     //     524,288 B  -> total ~152.5 MB
  u16* O_bf  = u_bf;
  u16* w2_bf = w1_bf;

  cvt_bf16<<<16384, 256, 0, stream>>>(u, u_bf);          // 16.7M elems
  cvt_bf16<<<12288, 256, 0, stream>>>(Wqkv, w1_bf);      // 12.6M elems
  rope_tab_k<<<256, 256, 0, stream>>>(tab);
  gemm_bt<true><<<dim3(48, 64), 256, 0, stream>>>(u_bf, w1_bf, bqkv, qkv_bf, nullptr, 6144);
  rope_apply_k<<<32768, 256, 0, stream>>>(qkv_bf, tab);
  attn_k<<<4096, 256, 0, stream>>>(qkv_bf, sinks, O_bf);
  cvt_bf16<<<4096, 256, 0, stream>>>(Wo, w2_bf);         // 4.2M elems
  gemm_bt<false><<<dim3(16, 64), 256, 0, stream>>>(O_bf, w2_bf, bo, nullptr, out, 2048);
}

// Round 2
// 556.415 us; speedup vs baseline: 1.1223x; 1.1223x over previous
//
#include <hip/hip_runtime.h>
#include <hip/hip_bf16.h>

typedef unsigned short u16;
typedef __attribute__((ext_vector_type(8))) short bf16x8;
typedef __attribute__((ext_vector_type(4))) float f32x4;

__device__ __forceinline__ u16 f2b(float f) {
  union { __hip_bfloat16 h; u16 u; } cv;
  cv.h = __float2bfloat16(f);
  return cv.u;
}
__device__ __forceinline__ float b2f(u16 u) {
  union { unsigned int i; float f; } cv;
  cv.i = ((unsigned int)u) << 16;
  return cv.f;
}

// ---------- f32 -> bf16 conversion, 4 elems/thread, exact grid ----------
__global__ void cvt_bf16(const float* __restrict__ in, u16* __restrict__ out) {
  size_t i = ((size_t)blockIdx.x * 256 + threadIdx.x) * 4;
  float4 v = *(const float4*)(in + i);
  ushort4 o;
  o.x = f2b(v.x); o.y = f2b(v.y); o.z = f2b(v.z); o.w = f2b(v.w);
  *(ushort4*)(out + i) = o;
}

// ---------- RoPE cos/sin table: [L=2048][half=32] ----------
__global__ void rope_tab_k(float2* __restrict__ tab) {
  int t = blockIdx.x * 256 + threadIdx.x;   // 65536
  int l = t >> 5, i = t & 31;
  float inv = powf(10000.0f, -(float)i * (1.0f / 32.0f));
  float ang = (float)l * inv;
  tab[t] = make_float2(cosf(ang), sinf(ang));
}

// ---------- deep-pipelined 256x256 GEMM, K=2048, counted-vmcnt 4-slot rotation ----
// C[m,n] = sum_k A[m,k]*B[n,k] (+bias), A:[M][2048], B:[N][2048] bf16 row-major.
// 512 thr = 8 waves (2Mx4N), per-wave C = 128x64. K-slices of 32 rotate through
// 4 LDS slots per operand (4x16KB A + 4x16KB B = 128 KiB). Slice j read at phase j,
// slice j+3 staged at phase j, vmcnt(8) keeps 2 slices in flight across barriers.
// LDS swizzle: 16B-slot s stored at s ^ ((row>>1)&3)  (both-sides: pre-swizzled
// global source on the write path, XOR on the read path).
template<int NCOLS, bool ROPE>
__global__ __launch_bounds__(512, 2) void gemm_p(const u16* __restrict__ A,
                                                 const u16* __restrict__ Bm,
                                                 const float* __restrict__ bias,
                                                 u16* __restrict__ Cb,
                                                 float* __restrict__ Cf,
                                                 const float2* __restrict__ tab) {
  extern __shared__ char smem[];
  u16* Asl = (u16*)smem;              // 4 slots x 8192 u16 (16KB): [256 rows][32 k]
  u16* Bsl = (u16*)(smem + 65536);
  const int tid = threadIdx.x, lane = tid & 63, w = tid >> 6;
  const int wr = w >> 2, wcn = w & 3;
  const int fr = lane & 15, fk = lane >> 4;
  const int m0 = blockIdx.y * 256, n0 = blockIdx.x * 256;
  const int srow = lane >> 2;                       // staging row within 16-row chunk
  const int gslot = (lane & 3) ^ ((lane >> 3) & 3); // pre-swizzled global 16B slot
  const int c0 = w * 2, c1 = c0 + 1;                // this wave's two chunks
  const int sel = (fr >> 1) & 3;
  const int ka = (fk ^ sel) << 4;                   // swizzled 16B slot on read path
  f32x4 acc[8][4] = {};

  auto stage = [&](int jj) {
    int slot = jj & 3;
    int kk = jj * 32 + gslot * 8;
    u16* Ad = Asl + slot * 8192;
    u16* Bd = Bsl + slot * 8192;
    const u16* gA0 = A  + (size_t)(m0 + c0 * 16 + srow) * 2048 + kk;
    const u16* gA1 = A  + (size_t)(m0 + c1 * 16 + srow) * 2048 + kk;
    const u16* gB0 = Bm + (size_t)(n0 + c0 * 16 + srow) * 2048 + kk;
    const u16* gB1 = Bm + (size_t)(n0 + c1 * 16 + srow) * 2048 + kk;
    __builtin_amdgcn_global_load_lds((const __attribute__((address_space(1))) unsigned int*)gA0,
        (__attribute__((address_space(3))) unsigned int*)(Ad + c0 * 512), 16, 0, 0);
    __builtin_amdgcn_global_load_lds((const __attribute__((address_space(1))) unsigned int*)gA1,
        (__attribute__((address_space(3))) unsigned int*)(Ad + c1 * 512), 16, 0, 0);
    __builtin_amdgcn_global_load_lds((const __attribute__((address_space(1))) unsigned int*)gB0,
        (__attribute__((address_space(3))) unsigned int*)(Bd + c0 * 512), 16, 0, 0);
    __builtin_amdgcn_global_load_lds((const __attribute__((address_space(1))) unsigned int*)gB1,
        (__attribute__((address_space(3))) unsigned int*)(Bd + c1 * 512), 16, 0, 0);
  };

  stage(0); stage(1); stage(2);
  asm volatile("s_waitcnt vmcnt(8)" ::: "memory");   // slice 0 (own loads) landed
  asm volatile("s_barrier" ::: "memory");            // -> slice 0 fully resident

  for (int j = 0; j < 64; ++j) {
    if (j < 61) stage(j + 3);
    const char* Ab = (const char*)(Asl + (j & 3) * 8192);
    const char* Bb = (const char*)(Bsl + (j & 3) * 8192);
    bf16x8 af[8], bv[4];
    #pragma unroll
    for (int m = 0; m < 8; ++m)
      af[m] = *(const bf16x8*)(Ab + (wr * 128 + m * 16 + fr) * 64 + ka);
    #pragma unroll
    for (int n = 0; n < 4; ++n)
      bv[n] = *(const bf16x8*)(Bb + (wcn * 64 + n * 16 + fr) * 64 + ka);
    __builtin_amdgcn_s_setprio(1);
    #pragma unroll
    for (int m = 0; m < 8; ++m)
      #pragma unroll
      for (int n = 0; n < 4; ++n)
        acc[m][n] = __builtin_amdgcn_mfma_f32_16x16x32_bf16(af[m], bv[n], acc[m][n], 0, 0, 0);
    __builtin_amdgcn_s_setprio(0);
    if (j < 61)       asm volatile("s_waitcnt vmcnt(8)" ::: "memory"); // slice j+1 landed
    else if (j == 61) asm volatile("s_waitcnt vmcnt(4)" ::: "memory");
    else if (j == 62) asm volatile("s_waitcnt vmcnt(0)" ::: "memory");
    asm volatile("s_waitcnt lgkmcnt(0)" ::: "memory"); // ds_reads drained before barrier
    asm volatile("s_barrier" ::: "memory");
  }

  // ---- epilogue: bias (+ fused RoPE for q,k cols when ROPE) ----
  #pragma unroll
  for (int m = 0; m < 8; ++m) {
    int grow0 = m0 + wr * 128 + m * 16 + fk * 4;
    #pragma unroll
    for (int n = 0; n < 4; ++n) {
      int gcol = n0 + wcn * 64 + n * 16 + fr;
      if (ROPE) {
        if (gcol < 4096) {
          int c = gcol & 63;
          int i = c & 31;
          bool lo = c < 32;
          float bx = bias[gcol], bp = bias[gcol ^ 32];
          #pragma unroll
          for (int r = 0; r < 4; ++r) {
            int t = grow0 + r;
            float2 cs = tab[((t & 2047) << 5) + i];
            float xb = acc[m][n][r] + bx;          // this column
            float pb = acc[m][n ^ 2][r] + bp;      // partner column (gcol^32)
            float o = lo ? (xb * cs.x - pb * cs.y) : (pb * cs.y + xb * cs.x);
            Cb[(size_t)t * NCOLS + gcol] = f2b(o);
          }
        } else {
          float bx = bias[gcol];
          #pragma unroll
          for (int r = 0; r < 4; ++r)
            Cb[(size_t)(grow0 + r) * NCOLS + gcol] = f2b(acc[m][n][r] + bx);
        }
      } else {
        float bx = bias[gcol];
        #pragma unroll
        for (int r = 0; r < 4; ++r)
          Cf[(size_t)(grow0 + r) * NCOLS + gcol] = acc[m][n][r] + bx;
      }
    }
  }
}

// ---------- banded attention with sinks ----------
// block = (b, h, n); 4 waves x 16 q-rows. Keys: [0,16)=sinks, [16,208)=band, [208,224)=pad
#define PSTR 232
__global__ __launch_bounds__(256) void attn_k(const u16* __restrict__ qkv,
                                              const float* __restrict__ sinks,
                                              u16* __restrict__ O) {
  __shared__ char smem[59392];
  char* Kraw = smem;                      // phase 1: K_all [224][64] bf16, XOR-swizzled
  char* Qraw = smem + 28672;              // phase 1: Q [64][64] bf16, XOR-swizzled
  u16* Ps = (u16*)smem;                   // phase 2: P [64][PSTR]
  u16* Vt = (u16*)(smem + 29696);         // phase 2: V^T [64][PSTR]
  const int tid = threadIdx.x, lane = tid & 63, wid = tid >> 6;
  const int fr = lane & 15, fk = lane >> 4;
  const int bx = blockIdx.x;
  const int n = bx & 31, h = (bx >> 5) & 31, b = bx >> 10;
  const size_t qrow0 = (size_t)b * 2048 + n * 64;

  // ---- phase 1: stage Q and K_all
  for (int c = tid; c < 512; c += 256) {          // Q: 64 rows x 128B
    int row = c >> 3, colb = (c & 7) * 16;
    uint4 v = *(const uint4*)((const char*)(qkv + (qrow0 + row) * 6144 + h * 64) + colb);
    *(uint4*)(Qraw + ((row * 128 + colb) ^ ((row & 7) << 4))) = v;
  }
  {                                               // sinks -> K rows 0..15 (fp32->bf16)
    int row = tid >> 4, col4 = (tid & 15) * 4;
    float4 v = *(const float4*)(sinks + ((size_t)h * 16 + row) * 64 + col4);
    ushort4 o; o.x = f2b(v.x); o.y = f2b(v.y); o.z = f2b(v.z); o.w = f2b(v.w);
    *(ushort4*)(Kraw + ((row * 128 + col4 * 2) ^ ((row & 7) << 4))) = o;
  }
  for (int c = tid; c < 1536; c += 256) {         // band K -> rows 16..207
    int kidx = c >> 3, colb = (c & 7) * 16;
    int blk = n - 1 + (kidx >> 6);
    int blkc = min(max(blk, 0), 31);
    int kpos = blkc * 64 + (kidx & 63);
    uint4 v = *(const uint4*)((const char*)(qkv + ((size_t)b * 2048 + kpos) * 6144 + 2048 + h * 64) + colb);
    int row = 16 + kidx;
    *(uint4*)(Kraw + ((row * 128 + colb) ^ ((row & 7) << 4))) = v;
  }
  if (tid < 128) {                                // zero pad rows 208..223
    int row = 208 + (tid >> 3), colb = (tid & 7) * 16;
    uint4 z = {0, 0, 0, 0};
    *(uint4*)(Kraw + ((row * 128 + colb) ^ ((row & 7) << 4))) = z;
  }
  __syncthreads();

  // ---- phase 2: QK^T (MFMA) + masked softmax in registers
  bf16x8 qf[2];
  {
    int qrow = wid * 16 + fr;
    #pragma unroll
    for (int kc = 0; kc < 2; ++kc)
      qf[kc] = *(const bf16x8*)(Qraw + ((qrow * 128 + kc * 64 + fk * 16) ^ ((qrow & 7) << 4)));
  }
  f32x4 sacc[14];
  #pragma unroll
  for (int g = 0; g < 14; ++g) {
    int key = g * 16 + fr;
    bf16x8 kf0 = *(const bf16x8*)(Kraw + ((key * 128 + fk * 16) ^ ((key & 7) << 4)));
    bf16x8 kf1 = *(const bf16x8*)(Kraw + ((key * 128 + 64 + fk * 16) ^ ((key & 7) << 4)));
    f32x4 a = {};
    a = __builtin_amdgcn_mfma_f32_16x16x32_bf16(qf[0], kf0, a, 0, 0, 0);
    a = __builtin_amdgcn_mfma_f32_16x16x32_bf16(qf[1], kf1, a, 0, 0, 0);
    sacc[g] = a;
  }
  float rowmax[4] = {-3e38f, -3e38f, -3e38f, -3e38f};
  #pragma unroll
  for (int g = 0; g < 14; ++g) {
    int key = g * 16 + fr;
    #pragma unroll
    for (int r = 0; r < 4; ++r) {
      float s = sacc[g][r] * 0.125f;
      bool valid;
      if (key < 16) valid = true;
      else if (key < 208) {
        int kidx = key - 16;
        int blk = n - 1 + (kidx >> 6);
        int kpos = blk * 64 + (kidx & 63);
        int qpos = n * 64 + wid * 16 + fk * 4 + r;
        valid = (blk >= 0) && (blk < 32) && (qpos - kpos <= 64) && (kpos - qpos <= 64);
      } else valid = false;
      s = valid ? s : -1e30f;
      sacc[g][r] = s;
      rowmax[r] = fmaxf(rowmax[r], s);
    }
  }
  #pragma unroll
  for (int d = 1; d < 16; d <<= 1)
    #pragma unroll
    for (int r = 0; r < 4; ++r)
      rowmax[r] = fmaxf(rowmax[r], __shfl_xor(rowmax[r], d));
  float rowsum[4] = {0, 0, 0, 0};
  #pragma unroll
  for (int g = 0; g < 14; ++g)
    #pragma unroll
    for (int r = 0; r < 4; ++r) {
      float p = __expf(sacc[g][r] - rowmax[r]);
      sacc[g][r] = p;
      rowsum[r] += p;
    }
  #pragma unroll
  for (int d = 1; d < 16; d <<= 1)
    #pragma unroll
    for (int r = 0; r < 4; ++r)
      rowsum[r] += __shfl_xor(rowsum[r], d);
  __syncthreads();   // Kall/Q now dead; P/Vt regions become writable

  // ---- phase 3: write unnormalized P (bf16), stage V transposed
  #pragma unroll
  for (int g = 0; g < 14; ++g)
    #pragma unroll
    for (int r = 0; r < 4; ++r)
      Ps[(wid * 16 + fk * 4 + r) * PSTR + g * 16 + fr] = f2b(sacc[g][r]);
  {
    int dout = tid & 63, kb = tid >> 6;
    #pragma unroll
    for (int key = kb; key < 16; key += 4)        // sink V rows
      Vt[dout * PSTR + key] = f2b(sinks[((size_t)h * 16 + key) * 64 + dout]);
    for (int kidx = kb; kidx < 192; kidx += 4) {  // band V rows
      int blk = n - 1 + (kidx >> 6);
      int blkc = min(max(blk, 0), 31);
      int kpos = blkc * 64 + (kidx & 63);
      Vt[dout * PSTR + 16 + kidx] = qkv[((size_t)b * 2048 + kpos) * 6144 + 4096 + h * 64 + dout];
    }
    #pragma unroll
    for (int key = 208 + kb; key < 224; key += 4) // zero the pad keys
      Vt[dout * PSTR + key] = 0;
  }
  __syncthreads();

  // ---- phase 4: O = P * V
  f32x4 oacc[4] = {};
  #pragma unroll
  for (int kc = 0; kc < 7; ++kc) {
    bf16x8 pf = *(const bf16x8*)(Ps + (wid * 16 + fr) * PSTR + kc * 32 + fk * 8);
    #pragma unroll
    for (int gd = 0; gd < 4; ++gd) {
      bf16x8 vf = *(const bf16x8*)(Vt + (gd * 16 + fr) * PSTR + kc * 32 + fk * 8);
      oacc[gd] = __builtin_amdgcn_mfma_f32_16x16x32_bf16(pf, vf, oacc[gd], 0, 0, 0);
    }
  }
  #pragma unroll
  for (int gd = 0; gd < 4; ++gd)
    #pragma unroll
    for (int r = 0; r < 4; ++r) {
      int qrl = wid * 16 + fk * 4 + r;
      float v = oacc[gd][r] / rowsum[r];
      O[(qrow0 + qrl) * 2048 + h * 64 + gd * 16 + fr] = f2b(v);
    }
}

extern "C" void kernel_launch(void* const* d_in, const int* in_sizes, int n_in,
                              void* d_out, int out_size, void* d_ws, size_t ws_size,
                              hipStream_t stream) {
  const float* u     = (const float*)d_in[0];
  const float* Wqkv  = (const float*)d_in[1];
  const float* bqkv  = (const float*)d_in[2];
  const float* Wo    = (const float*)d_in[3];
  const float* bo    = (const float*)d_in[4];
  const float* sinks = (const float*)d_in[5];
  float* out = (float*)d_out;

  char* ws = (char*)d_ws;
  u16* u_bf   = (u16*)ws;                      // 33,554,432 B  (reused as O_bf)
  u16* w1_bf  = (u16*)(ws + 33554432);         // 25,165,824 B  (reused for Wo)
  u16* qkv_bf = (u16*)(ws + 58720256);         // 100,663,296 B
  float2* tab = (float2*)(ws + 159383552);     //     524,288 B
  u16* O_bf  = u_bf;
  u16* w2_bf = w1_bf;

  hipFuncSetAttribute((const void*)gemm_p<6144, true>,
                      hipFuncAttributeMaxDynamicSharedMemorySize, 131072);
  hipFuncSetAttribute((const void*)gemm_p<2048, false>,
                      hipFuncAttributeMaxDynamicSharedMemorySize, 131072);

  cvt_bf16<<<16384, 256, 0, stream>>>(u, u_bf);          // 16.7M elems
  cvt_bf16<<<12288, 256, 0, stream>>>(Wqkv, w1_bf);      // 12.6M elems
  rope_tab_k<<<256, 256, 0, stream>>>(tab);
  gemm_p<6144, true><<<dim3(24, 32), 512, 131072, stream>>>(u_bf, w1_bf, bqkv, qkv_bf, nullptr, tab);
  attn_k<<<4096, 256, 0, stream>>>(qkv_bf, sinks, O_bf);
  cvt_bf16<<<4096, 256, 0, stream>>>(Wo, w2_bf);         // 4.2M elems
  gemm_p<2048, false><<<dim3(8, 32), 512, 131072, stream>>>(O_bf, w2_bf, bo, nullptr, out, nullptr);
}

// Round 5
// 521.329 us; speedup vs baseline: 1.1978x; 1.0673x over previous
//
#include <hip/hip_runtime.h>
#include <hip/hip_bf16.h>

typedef unsigned short u16;
typedef __attribute__((ext_vector_type(8))) short bf16x8;
typedef __attribute__((ext_vector_type(4))) float f32x4;

__device__ __forceinline__ u16 f2b(float f) {
  union { __hip_bfloat16 h; u16 u; } cv;
  cv.h = __float2bfloat16(f);
  return cv.u;
}
__device__ __forceinline__ float b2f(u16 u) {
  union { unsigned int i; float f; } cv;
  cv.i = ((unsigned int)u) << 16;
  return cv.f;
}

// ---------- f32 -> bf16 conversion, 4 elems/thread, exact grid ----------
__global__ void cvt_bf16(const float* __restrict__ in, u16* __restrict__ out) {
  size_t i = ((size_t)blockIdx.x * 256 + threadIdx.x) * 4;
  float4 v = *(const float4*)(in + i);
  ushort4 o;
  o.x = f2b(v.x); o.y = f2b(v.y); o.z = f2b(v.z); o.w = f2b(v.w);
  *(ushort4*)(out + i) = o;
}

// ---------- RoPE cos/sin table: [L=2048][half=32] ----------
__global__ void rope_tab_k(float2* __restrict__ tab) {
  int t = blockIdx.x * 256 + threadIdx.x;   // 65536
  int l = t >> 5, i = t & 31;
  float inv = powf(10000.0f, -(float)i * (1.0f / 32.0f));
  float ang = (float)l * inv;
  tab[t] = make_float2(cosf(ang), sinf(ang));
}

// ---------- deep-pipelined 256x256 GEMM, 8-phase-style interleave ----------
// C[m,n] = sum_k A[m,k]*B[n,k] (+bias). Per phase: stage(j+3); ds_read slice j
// (pre-barrier, latency absorbed by barrier wait); barrier; lgkmcnt(0);
// sched_barrier; setprio(1) 32xMFMA setprio(0); vmcnt(8) counted; barrier.
// Slot safety: stage(j+4)@phase j+1 hits slot j&3; its reads drained by every
// wave's lgkmcnt(0) before barrier-2 of phase j. Stage-to-read dist = 3 phases.
template<int NCOLS, bool ROPE>
__global__ __launch_bounds__(512, 2) void gemm_p(const u16* __restrict__ A,
                                                 const u16* __restrict__ Bm,
                                                 const float* __restrict__ bias,
                                                 u16* __restrict__ Cb,
                                                 float* __restrict__ Cf,
                                                 const float2* __restrict__ tab) {
  extern __shared__ char smem[];
  u16* Asl = (u16*)smem;              // 4 slots x 8192 u16 (16KB): [256 rows][32 k]
  u16* Bsl = (u16*)(smem + 65536);
  const int tid = threadIdx.x, lane = tid & 63, w = tid >> 6;
  const int wr = w >> 2, wcn = w & 3;
  const int fr = lane & 15, fk = lane >> 4;
  const int m0 = blockIdx.y * 256, n0 = blockIdx.x * 256;
  const int srow = lane >> 2;                       // staging row within 16-row chunk
  const int gslot = (lane & 3) ^ ((lane >> 3) & 3); // pre-swizzled global 16B slot
  const int c0 = w * 2, c1 = c0 + 1;                // this wave's two chunks
  const int sel = (fr >> 1) & 3;
  const int ka = (fk ^ sel) << 4;                   // swizzled 16B slot on read path
  f32x4 acc[8][4] = {};

  auto stage = [&](int jj) {
    int slot = jj & 3;
    int kk = jj * 32 + gslot * 8;
    u16* Ad = Asl + slot * 8192;
    u16* Bd = Bsl + slot * 8192;
    const u16* gA0 = A  + (size_t)(m0 + c0 * 16 + srow) * 2048 + kk;
    const u16* gA1 = A  + (size_t)(m0 + c1 * 16 + srow) * 2048 + kk;
    const u16* gB0 = Bm + (size_t)(n0 + c0 * 16 + srow) * 2048 + kk;
    const u16* gB1 = Bm + (size_t)(n0 + c1 * 16 + srow) * 2048 + kk;
    __builtin_amdgcn_global_load_lds((const __attribute__((address_space(1))) unsigned int*)gA0,
        (__attribute__((address_space(3))) unsigned int*)(Ad + c0 * 512), 16, 0, 0);
    __builtin_amdgcn_global_load_lds((const __attribute__((address_space(1))) unsigned int*)gA1,
        (__attribute__((address_space(3))) unsigned int*)(Ad + c1 * 512), 16, 0, 0);
    __builtin_amdgcn_global_load_lds((const __attribute__((address_space(1))) unsigned int*)gB0,
        (__attribute__((address_space(3))) unsigned int*)(Bd + c0 * 512), 16, 0, 0);
    __builtin_amdgcn_global_load_lds((const __attribute__((address_space(1))) unsigned int*)gB1,
        (__attribute__((address_space(3))) unsigned int*)(Bd + c1 * 512), 16, 0, 0);
  };

  stage(0); stage(1); stage(2);
  asm volatile("s_waitcnt vmcnt(8)" ::: "memory");   // slice 0 landed
  asm volatile("s_barrier" ::: "memory");

  for (int j = 0; j < 64; ++j) {
    if (j < 61) stage(j + 3);
    const char* Ab = (const char*)(Asl + (j & 3) * 8192);
    const char* Bb = (const char*)(Bsl + (j & 3) * 8192);
    bf16x8 af[8], bv[4];
    #pragma unroll
    for (int n = 0; n < 4; ++n)
      bv[n] = *(const bf16x8*)(Bb + (wcn * 64 + n * 16 + fr) * 64 + ka);
    #pragma unroll
    for (int m = 0; m < 8; ++m)
      af[m] = *(const bf16x8*)(Ab + (wr * 128 + m * 16 + fr) * 64 + ka);
    asm volatile("s_barrier" ::: "memory");            // reads in flight across wait
    asm volatile("s_waitcnt lgkmcnt(0)" ::: "memory");
    __builtin_amdgcn_sched_barrier(0);                 // rule 18: pin MFMA below wait
    __builtin_amdgcn_s_setprio(1);
    #pragma unroll
    for (int m = 0; m < 8; ++m)
      #pragma unroll
      for (int n = 0; n < 4; ++n)
        acc[m][n] = __builtin_amdgcn_mfma_f32_16x16x32_bf16(af[m], bv[n], acc[m][n], 0, 0, 0);
    __builtin_amdgcn_s_setprio(0);
    __builtin_amdgcn_sched_barrier(0);
    if (j < 61)       asm volatile("s_waitcnt vmcnt(8)" ::: "memory"); // slice j+1 landed
    else if (j == 61) asm volatile("s_waitcnt vmcnt(4)" ::: "memory");
    else if (j == 62) asm volatile("s_waitcnt vmcnt(0)" ::: "memory");
    asm volatile("s_barrier" ::: "memory");
  }

  // ---- epilogue: bias (+ fused RoPE for q,k cols when ROPE) ----
  #pragma unroll
  for (int m = 0; m < 8; ++m) {
    int grow0 = m0 + wr * 128 + m * 16 + fk * 4;
    #pragma unroll
    for (int n = 0; n < 4; ++n) {
      int gcol = n0 + wcn * 64 + n * 16 + fr;
      if (ROPE) {
        if (gcol < 4096) {
          int c = gcol & 63;
          int i = c & 31;
          bool lo = c < 32;
          float bx = bias[gcol], bp = bias[gcol ^ 32];
          #pragma unroll
          for (int r = 0; r < 4; ++r) {
            int t = grow0 + r;
            float2 cs = tab[((t & 2047) << 5) + i];
            float xb = acc[m][n][r] + bx;          // this column
            float pb = acc[m][n ^ 2][r] + bp;      // partner column (gcol^32)
            float o = lo ? (xb * cs.x - pb * cs.y) : (pb * cs.y + xb * cs.x);
            Cb[(size_t)t * NCOLS + gcol] = f2b(o);
          }
        } else {
          float bx = bias[gcol];
          #pragma unroll
          for (int r = 0; r < 4; ++r)
            Cb[(size_t)(grow0 + r) * NCOLS + gcol] = f2b(acc[m][n][r] + bx);
        }
      } else {
        float bx = bias[gcol];
        #pragma unroll
        for (int r = 0; r < 4; ++r)
          Cf[(size_t)(grow0 + r) * NCOLS + gcol] = acc[m][n][r] + bx;
      }
    }
  }
}

// ---------- banded attention with sinks ----------
// block = (b, h, n); 4 waves x 16 q-rows. Keys: [0,16)=sinks, [16,208)=band, [208,224)=pad
// Vt layout: [64 dout][32 granule slots of 8 keys], granule gi stored at slot
// gi ^ (dout&7) (slots 24..31 are swizzle images of group-3 granules), row 512B.
#define PSTR 232
__global__ __launch_bounds__(256) void attn_k(const u16* __restrict__ qkv,
                                              const float* __restrict__ sinks,
                                              u16* __restrict__ O) {
  extern __shared__ char smem[];          // 66816 B
  char* Kraw = smem;                      // phase 1: K_all [224][64] bf16, XOR-swizzled
  char* Qraw = smem + 28672;              // phase 1: Q [64][64] bf16, XOR-swizzled
  u16* Ps = (u16*)smem;                   // phase 3: P [64][PSTR]            (29696 B)
  u16* Vt = (u16*)(smem + 29696);         // phase 3: V^T [64][256] swizzled  (32768 B)
  char* tmpb = smem + 62464;              // phase 3: 4 waves x 1088B transpose tile
  const int tid = threadIdx.x, lane = tid & 63, wid = tid >> 6;
  const int fr = lane & 15, fk = lane >> 4;
  const int bx = blockIdx.x;
  const int n = bx & 31, h = (bx >> 5) & 31, b = bx >> 10;
  const size_t qrow0 = (size_t)b * 2048 + n * 64;

  // ---- phase 1: stage Q and K_all
  for (int c = tid; c < 512; c += 256) {          // Q: 64 rows x 128B
    int row = c >> 3, colb = (c & 7) * 16;
    uint4 v = *(const uint4*)((const char*)(qkv + (qrow0 + row) * 6144 + h * 64) + colb);
    *(uint4*)(Qraw + ((row * 128 + colb) ^ ((row & 7) << 4))) = v;
  }
  {                                               // sinks -> K rows 0..15 (fp32->bf16)
    int row = tid >> 4, col4 = (tid & 15) * 4;
    float4 v = *(const float4*)(sinks + ((size_t)h * 16 + row) * 64 + col4);
    ushort4 o; o.x = f2b(v.x); o.y = f2b(v.y); o.z = f2b(v.z); o.w = f2b(v.w);
    *(ushort4*)(Kraw + ((row * 128 + col4 * 2) ^ ((row & 7) << 4))) = o;
  }
  for (int c = tid; c < 1536; c += 256) {         // band K -> rows 16..207
    int kidx = c >> 3, colb = (c & 7) * 16;
    int blk = n - 1 + (kidx >> 6);
    int blkc = min(max(blk, 0), 31);
    int kpos = blkc * 64 + (kidx & 63);
    uint4 v = *(const uint4*)((const char*)(qkv + ((size_t)b * 2048 + kpos) * 6144 + 2048 + h * 64) + colb);
    int row = 16 + kidx;
    *(uint4*)(Kraw + ((row * 128 + colb) ^ ((row & 7) << 4))) = v;
  }
  if (tid < 128) {                                // zero pad rows 208..223
    int row = 208 + (tid >> 3), colb = (tid & 7) * 16;
    uint4 z = {0, 0, 0, 0};
    *(uint4*)(Kraw + ((row * 128 + colb) ^ ((row & 7) << 4))) = z;
  }
  __syncthreads();

  // ---- phase 2: QK^T (MFMA) + masked softmax in registers
  bf16x8 qf[2];
  {
    int qrow = wid * 16 + fr;
    #pragma unroll
    for (int kc = 0; kc < 2; ++kc)
      qf[kc] = *(const bf16x8*)(Qraw + ((qrow * 128 + kc * 64 + fk * 16) ^ ((qrow & 7) << 4)));
  }
  f32x4 sacc[14];
  #pragma unroll
  for (int g = 0; g < 14; ++g) {
    int key = g * 16 + fr;
    bf16x8 kf0 = *(const bf16x8*)(Kraw + ((key * 128 + fk * 16) ^ ((key & 7) << 4)));
    bf16x8 kf1 = *(const bf16x8*)(Kraw + ((key * 128 + 64 + fk * 16) ^ ((key & 7) << 4)));
    f32x4 a = {};
    a = __builtin_amdgcn_mfma_f32_16x16x32_bf16(qf[0], kf0, a, 0, 0, 0);
    a = __builtin_amdgcn_mfma_f32_16x16x32_bf16(qf[1], kf1, a, 0, 0, 0);
    sacc[g] = a;
  }
  float rowmax[4] = {-3e38f, -3e38f, -3e38f, -3e38f};
  #pragma unroll
  for (int g = 0; g < 14; ++g) {
    int key = g * 16 + fr;
    #pragma unroll
    for (int r = 0; r < 4; ++r) {
      float s = sacc[g][r] * 0.125f;
      bool valid;
      if (key < 16) valid = true;
      else if (key < 208) {
        int kidx = key - 16;
        int blk = n - 1 + (kidx >> 6);
        int kpos = blk * 64 + (kidx & 63);
        int qpos = n * 64 + wid * 16 + fk * 4 + r;
        valid = (blk >= 0) && (blk < 32) && (qpos - kpos <= 64) && (kpos - qpos <= 64);
      } else valid = false;
      s = valid ? s : -1e30f;
      sacc[g][r] = s;
      rowmax[r] = fmaxf(rowmax[r], s);
    }
  }
  #pragma unroll
  for (int d = 1; d < 16; d <<= 1)
    #pragma unroll
    for (int r = 0; r < 4; ++r)
      rowmax[r] = fmaxf(rowmax[r], __shfl_xor(rowmax[r], d));
  float rowsum[4] = {0, 0, 0, 0};
  #pragma unroll
  for (int g = 0; g < 14; ++g)
    #pragma unroll
    for (int r = 0; r < 4; ++r) {
      float p = __expf(sacc[g][r] - rowmax[r]);
      sacc[g][r] = p;
      rowsum[r] += p;
    }
  #pragma unroll
  for (int d = 1; d < 16; d <<= 1)
    #pragma unroll
    for (int r = 0; r < 4; ++r)
      rowsum[r] += __shfl_xor(rowsum[r], d);
  __syncthreads();   // Kall/Q now dead; Ps/Vt/tmp regions become writable

  // ---- phase 3: write unnormalized P (bf16); stage V via coalesced load +
  //      per-wave LDS transpose tile -> packed b128 writes into swizzled Vt.
  #pragma unroll
  for (int g = 0; g < 14; ++g)
    #pragma unroll
    for (int r = 0; r < 4; ++r)
      Ps[(wid * 16 + fk * 4 + r) * PSTR + g * 16 + fr] = f2b(sacc[g][r]);

  {
    u16* tw = (u16*)(tmpb + wid * 1088);  // per-wave [8 keys][68 u16] (136B rows)
    const int g = lane >> 3, s = lane & 7; // key sub-idx, dout-group
    // sinks (granules 0,1 by waves 0,1) + zero-pad (granules 26,27 by waves 2,3)
    if (wid < 2) {
      int key = wid * 8 + g;
      float4 v0 = *(const float4*)(sinks + ((size_t)h * 16 + key) * 64 + s * 8);
      float4 v1 = *(const float4*)(sinks + ((size_t)h * 16 + key) * 64 + s * 8 + 4);
      u16* dst = tw + g * 68 + s * 8;
      dst[0] = f2b(v0.x); dst[1] = f2b(v0.y); dst[2] = f2b(v0.z); dst[3] = f2b(v0.w);
      dst[4] = f2b(v1.x); dst[5] = f2b(v1.y); dst[6] = f2b(v1.z); dst[7] = f2b(v1.w);
      u16 col[8];
      #pragma unroll
      for (int k = 0; k < 8; ++k) col[k] = tw[k * 68 + lane];
      *(bf16x8*)(Vt + lane * 256 + ((wid ^ (lane & 7)) * 8)) = *(bf16x8*)col;
    } else {
      bf16x8 z = {};
      *(bf16x8*)(Vt + lane * 256 + (((24 + wid) ^ (lane & 7)) * 8)) = z;  // 26,27
    }
    // band V: 6 iters x (wave covers 8 keys x 64 dout)
    for (int it = 0; it < 6; ++it) {
      int kidx = it * 32 + wid * 8 + g;          // 0..191
      int blk = n - 1 + (kidx >> 6);
      int blkc = min(max(blk, 0), 31);
      int kpos = blkc * 64 + (kidx & 63);
      uint4 v = *(const uint4*)(qkv + ((size_t)b * 2048 + kpos) * 6144 + 4096 + h * 64 + s * 8);
      *(uint4*)(tw + g * 68 + s * 8) = v;
      u16 col[8];
      #pragma unroll
      for (int k = 0; k < 8; ++k) col[k] = tw[k * 68 + lane];
      int gi = 2 + it * 4 + wid;                 // granule 2..25
      *(bf16x8*)(Vt + lane * 256 + ((gi ^ (lane & 7)) * 8)) = *(bf16x8*)col;
    }
  }
  __syncthreads();

  // ---- phase 4: O = P * V  (B-frag from swizzled Vt granules)
  f32x4 oacc[4] = {};
  #pragma unroll
  for (int kc = 0; kc < 7; ++kc) {
    bf16x8 pf = *(const bf16x8*)(Ps + (wid * 16 + fr) * PSTR + kc * 32 + fk * 8);
    #pragma unroll
    for (int gd = 0; gd < 4; ++gd) {
      bf16x8 vf = *(const bf16x8*)(Vt + (gd * 16 + fr) * 256 + (((kc * 4 + fk) ^ (fr & 7)) * 8));
      oacc[gd] = __builtin_amdgcn_mfma_f32_16x16x32_bf16(pf, vf, oacc[gd], 0, 0, 0);
    }
  }
  #pragma unroll
  for (int gd = 0; gd < 4; ++gd)
    #pragma unroll
    for (int r = 0; r < 4; ++r) {
      int qrl = wid * 16 + fk * 4 + r;
      float v = oacc[gd][r] / rowsum[r];
      O[(qrow0 + qrl) * 2048 + h * 64 + gd * 16 + fr] = f2b(v);
    }
}

extern "C" void kernel_launch(void* const* d_in, const int* in_sizes, int n_in,
                              void* d_out, int out_size, void* d_ws, size_t ws_size,
                              hipStream_t stream) {
  const float* u     = (const float*)d_in[0];
  const float* Wqkv  = (const float*)d_in[1];
  const float* bqkv  = (const float*)d_in[2];
  const float* Wo    = (const float*)d_in[3];
  const float* bo    = (const float*)d_in[4];
  const float* sinks = (const float*)d_in[5];
  float* out = (float*)d_out;

  char* ws = (char*)d_ws;
  u16* u_bf   = (u16*)ws;                      // 33,554,432 B  (reused as O_bf)
  u16* w1_bf  = (u16*)(ws + 33554432);         // 25,165,824 B  (reused for Wo)
  u16* qkv_bf = (u16*)(ws + 58720256);         // 100,663,296 B
  float2* tab = (float2*)(ws + 159383552);     //     524,288 B
  u16* O_bf  = u_bf;
  u16* w2_bf = w1_bf;

  hipFuncSetAttribute((const void*)gemm_p<6144, true>,
                      hipFuncAttributeMaxDynamicSharedMemorySize, 131072);
  hipFuncSetAttribute((const void*)gemm_p<2048, false>,
                      hipFuncAttributeMaxDynamicSharedMemorySize, 131072);
  hipFuncSetAttribute((const void*)attn_k,
                      hipFuncAttributeMaxDynamicSharedMemorySize, 66816);

  cvt_bf16<<<16384, 256, 0, stream>>>(u, u_bf);          // 16.7M elems
  cvt_bf16<<<12288, 256, 0, stream>>>(Wqkv, w1_bf);      // 12.6M elems
  rope_tab_k<<<256, 256, 0, stream>>>(tab);
  gemm_p<6144, true><<<dim3(24, 32), 512, 131072, stream>>>(u_bf, w1_bf, bqkv, qkv_bf, nullptr, tab);
  attn_k<<<4096, 256, 66816, stream>>>(qkv_bf, sinks, O_bf);
  cvt_bf16<<<4096, 256, 0, stream>>>(Wo, w2_bf);         // 4.2M elems
  gemm_p<2048, false><<<dim3(8, 32), 512, 131072, stream>>>(O_bf, w2_bf, bo, nullptr, out, nullptr);
}